// Round 1
// baseline (738.540 us; speedup 1.0000x reference)
//
#include <hip/hip_runtime.h>
#include <math.h>

static inline int cdiv(long long a, int b){ return (int)((a + b - 1) / b); }

// ---------- up-projection: up[n*8+k][d] = relu(x[n]·W_up[k][:,d] + b_up[d]) ----------
__global__ void k_up(const float* __restrict__ x, const float* __restrict__ Wup,
                     const float* __restrict__ bup, float* __restrict__ outr, int n_out){
  int idx = blockIdx.x*blockDim.x + threadIdx.x;
  if (idx >= n_out*32) return;
  int row = idx >> 5, d = idx & 31;
  int n = row >> 3, k = row & 7;
  const float* xr = x + n*64;
  const float* w  = Wup + k*(64*32) + d;
  float s = bup[d];
#pragma unroll
  for (int c = 0; c < 64; ++c) s = fmaf(xr[c], w[c*32], s);
  outr[idx] = fmaxf(s, 0.f);
}

// ---------- init accumulator rows to bias ----------
template<int C>
__global__ void k_init(float* __restrict__ f, const float* __restrict__ b, int n_out){
  int idx = blockIdx.x*blockDim.x + threadIdx.x;
  if (idx >= n_out*C) return;
  f[idx] = b[idx % C];
}

// ---------- sparse conv scatter: one thread per (pair-slot, c_out) ----------
template<int CIN, int COUT>
__global__ void k_sconv(const float* __restrict__ fin, const float* __restrict__ W,
                        const int* __restrict__ nin, const int* __restrict__ nout,
                        float* __restrict__ facc, int P, int n_out){
  int gid = blockIdx.x*blockDim.x + threadIdx.x;
  int pair = gid / COUT;
  int lane = gid - pair*COUT;
  if (pair >= 27*P) return;
  int oi = nout[pair];
  if (oi >= n_out) return;           // padded slot
  int ii = nin[pair];
  int k  = pair / P;
  const float* fr = fin + ii*CIN;
  const float* w  = W + k*CIN*COUT + lane;
  float s = 0.f;
#pragma unroll
  for (int c = 0; c < CIN; ++c) s = fmaf(fr[c], w[c*COUT], s);
  atomicAdd(&facc[oi*COUT + lane], s);
}

template<int C>
__global__ void k_relu(float* __restrict__ f, int n_out){
  int idx = blockIdx.x*blockDim.x + threadIdx.x;
  if (idx < n_out*C) f[idx] = fmaxf(f[idx], 0.f);
}

// ---------- dense per-row GEMV ----------
template<int CIN, int COUT, bool RELU>
__global__ void k_dense(const float* __restrict__ fin, const float* __restrict__ W,
                        const float* __restrict__ b, float* __restrict__ fout, int n_out){
  int idx = blockIdx.x*blockDim.x + threadIdx.x;
  if (idx >= n_out*COUT) return;
  int row = idx / COUT, d = idx - row*COUT;
  const float* fr = fin + row*CIN;
  float s = b[d];
#pragma unroll
  for (int c = 0; c < CIN; ++c) s = fmaf(fr[c], W[c*COUT + d], s);
  fout[idx] = RELU ? fmaxf(s, 0.f) : s;
}

// ---------- out += concat(p0, p1) ----------
__global__ void k_cat_res(float* __restrict__ out, const float* __restrict__ p0,
                          const float* __restrict__ p1, int n_out){
  int idx = blockIdx.x*blockDim.x + threadIdx.x;
  if (idx >= n_out*32) return;
  int row = idx >> 5, c = idx & 31;
  float v = (c < 16) ? p0[row*16 + c] : p1[row*16 + c - 16];
  out[idx] += v;
}

// ---------- max/argmax reduction (first-index tie-break, matches jnp.argmax) ----------
__global__ void k_reduce1(const float* __restrict__ s, float* __restrict__ pmax,
                          int* __restrict__ pidx, int n){
  __shared__ float sm[256]; __shared__ int si[256];
  int t = threadIdx.x;
  float v = -INFINITY; int vi = 0x7fffffff;
  for (int j = blockIdx.x*256 + t; j < n; j += gridDim.x*256){
    float w = s[j];
    if (w > v){ v = w; vi = j; }
  }
  sm[t] = v; si[t] = vi; __syncthreads();
  for (int o = 128; o > 0; o >>= 1){
    if (t < o){
      if (sm[t+o] > sm[t] || (sm[t+o] == sm[t] && si[t+o] < si[t])){ sm[t]=sm[t+o]; si[t]=si[t+o]; }
    }
    __syncthreads();
  }
  if (t == 0){ pmax[blockIdx.x] = sm[0]; pidx[blockIdx.x] = si[0]; }
}

__global__ void k_reduce2(const float* __restrict__ pmax, const int* __restrict__ pidx,
                          float* __restrict__ g, int nb){
  __shared__ float sm[256]; __shared__ int si[256];
  int t = threadIdx.x;
  sm[t] = (t < nb) ? pmax[t] : -INFINITY;
  si[t] = (t < nb) ? pidx[t] : 0x7fffffff;
  __syncthreads();
  for (int o = 128; o > 0; o >>= 1){
    if (t < o){
      if (sm[t+o] > sm[t] || (sm[t+o] == sm[t] && si[t+o] < si[t])){ sm[t]=sm[t+o]; si[t]=si[t+o]; }
    }
    __syncthreads();
  }
  if (t == 0){ g[0] = sm[0]; ((int*)g)[1] = si[0]; }
}

// ---------- finalize: keep mask, pruned out, flat output assembly ----------
__global__ void k_final(const float* __restrict__ out, const float* __restrict__ cls,
                        const int* __restrict__ target, const float* __restrict__ g,
                        float* __restrict__ dout, int n_out){
  int idx = blockIdx.x*blockDim.x + threadIdx.x;
  if (idx >= n_out*32) return;
  int row = idx >> 5, c = idx & 31;
  float s = cls[row];
  bool keep = s > 0.f;
  if (g[0] < 0.f) keep = keep || (row == ((const int*)g)[1]);
  float km = keep ? 1.f : 0.f;
  dout[idx] = out[idx] * km;
  if (c == 0){
    dout[(size_t)n_out*32 + row] = s;
    dout[(size_t)n_out*33 + row] = (target[row] != 0) ? 1.f : 0.f;
    dout[(size_t)n_out*34 + row] = km;
  }
}

extern "C" void kernel_launch(void* const* d_in, const int* in_sizes, int n_in,
                              void* d_out, int out_size, void* d_ws, size_t ws_size,
                              hipStream_t stream){
  const float* x      = (const float*)d_in[0];
  const float* W_up   = (const float*)d_in[1];
  const float* b_up   = (const float*)d_in[2];
  const float* W_conv = (const float*)d_in[3];
  const float* b_conv = (const float*)d_in[4];
  const float* Wb00   = (const float*)d_in[5];
  const float* bb00   = (const float*)d_in[6];
  const float* Wb01   = (const float*)d_in[7];
  const float* bb01   = (const float*)d_in[8];
  const float* Wb10   = (const float*)d_in[9];
  const float* bb10   = (const float*)d_in[10];
  const float* Wb11   = (const float*)d_in[11];
  const float* bb11   = (const float*)d_in[12];
  const float* Wb12   = (const float*)d_in[13];
  const float* bb12   = (const float*)d_in[14];
  const float* W_cls  = (const float*)d_in[15];
  const float* b_cls  = (const float*)d_in[16];
  const int*   nbr_in = (const int*)d_in[17];
  const int*   nbr_out= (const int*)d_in[18];
  const int*   target = (const int*)d_in[19];

  const int n_out = in_sizes[19];
  const int P     = in_sizes[17] / 27;
  const int pairsT = 27 * P;

  float* ws    = (float*)d_ws;
  float* f_out = ws;                          // N*32  (current "out")
  float* f_tmp = ws + (size_t)n_out*32;       // N*32  (relu(up))
  float* a8    = ws + (size_t)n_out*64;       // N*8
  float* b8    = ws + (size_t)n_out*72;       // N*8
  float* p0    = ws + (size_t)n_out*80;       // N*16
  float* p1    = ws + (size_t)n_out*96;       // N*16
  float* cls   = ws + (size_t)n_out*112;      // N
  float* pmax  = ws + (size_t)n_out*113;      // 256
  int*   pidx  = (int*)(ws + (size_t)n_out*113 + 256); // 256
  float* g     = ws + (size_t)n_out*113 + 512;         // [max, argmax]

  const int B = 256;

  // relu(up) -> f_tmp
  k_up<<<cdiv((long long)n_out*32,B),B,0,stream>>>(x, W_up, b_up, f_tmp, n_out);

  // out = relu(sconv(f_tmp, W_conv, b_conv))
  k_init<32><<<cdiv((long long)n_out*32,B),B,0,stream>>>(f_out, b_conv, n_out);
  k_sconv<32,32><<<cdiv((long long)pairsT*32,B),B,0,stream>>>(f_tmp, W_conv, nbr_in, nbr_out, f_out, P, n_out);
  k_relu<32><<<cdiv((long long)n_out*32,B),B,0,stream>>>(f_out, n_out);

  for (int l = 0; l < 3; ++l){
    // branch0: p0 = sconv(relu(sconv(out, Wb00)), Wb01)
    k_init<8><<<cdiv((long long)n_out*8,B),B,0,stream>>>(a8, bb00 + l*8, n_out);
    k_sconv<32,8><<<cdiv((long long)pairsT*8,B),B,0,stream>>>(f_out, Wb00 + (size_t)l*27*32*8, nbr_in, nbr_out, a8, P, n_out);
    k_relu<8><<<cdiv((long long)n_out*8,B),B,0,stream>>>(a8, n_out);
    k_init<16><<<cdiv((long long)n_out*16,B),B,0,stream>>>(p0, bb01 + l*16, n_out);
    k_sconv<8,16><<<cdiv((long long)pairsT*16,B),B,0,stream>>>(a8, Wb01 + (size_t)l*27*8*16, nbr_in, nbr_out, p0, P, n_out);
    // branch1: p1 = relu(sconv(relu(out@Wb10+b), Wb11)) @ Wb12 + b
    k_dense<32,8,true><<<cdiv((long long)n_out*8,B),B,0,stream>>>(f_out, Wb10 + (size_t)l*32*8, bb10 + l*8, b8, n_out);
    k_init<8><<<cdiv((long long)n_out*8,B),B,0,stream>>>(a8, bb11 + l*8, n_out);
    k_sconv<8,8><<<cdiv((long long)pairsT*8,B),B,0,stream>>>(b8, Wb11 + (size_t)l*27*8*8, nbr_in, nbr_out, a8, P, n_out);
    k_relu<8><<<cdiv((long long)n_out*8,B),B,0,stream>>>(a8, n_out);
    k_dense<8,16,false><<<cdiv((long long)n_out*16,B),B,0,stream>>>(a8, Wb12 + (size_t)l*8*16, bb12 + l*16, p1, n_out);
    // out += concat(p0, p1)
    k_cat_res<<<cdiv((long long)n_out*32,B),B,0,stream>>>(f_out, p0, p1, n_out);
  }

  // classifier conv 32->1
  k_init<1><<<cdiv((long long)n_out,B),B,0,stream>>>(cls, b_cls, n_out);
  k_sconv<32,1><<<cdiv((long long)pairsT,B),B,0,stream>>>(f_out, W_cls, nbr_in, nbr_out, cls, P, n_out);

  // max/argmax of score
  k_reduce1<<<256,256,0,stream>>>(cls, pmax, pidx, n_out);
  k_reduce2<<<1,256,0,stream>>>(pmax, pidx, g, 256);

  // assemble outputs
  k_final<<<cdiv((long long)n_out*32,B),B,0,stream>>>(f_out, cls, target, g, (float*)d_out, n_out);
}